// Round 17
// baseline (174.051 us; speedup 1.0000x reference)
//
#include <hip/hip_runtime.h>

#define KK 12
#define LL 4096
#define DD 128
#define NN 16
#define RR 8
#define NC 128             // chunks (one per block)
#define LC 32              // chunk length
#define XST 132            // x-tile / ybuf LDS stride (floats)
#define SDST 44            // x_dbl LDS row stride (floats)
#define XDBL_TILE (LC * SDST)   // 1408 floats per (k,chunk) tile

__device__ __forceinline__ int pos_of(int k, int l) {
    int o = k >> 1;
    int le = (k & 1) ? (4095 - l) : l;
    int t1 = le >> 8, t2 = (le >> 4) & 15, t3 = le & 15;
    switch (o) {
        case 0:  return (t1 << 8) | (t2 << 4) | t3;
        case 1:  return (t1 << 8) | (t3 << 4) | t2;
        case 2:  return (t3 << 8) | (t2 << 4) | t1;
        case 3:  return (t2 << 8) | (t3 << 4) | t1;
        case 4:  return (t2 << 8) | (t1 << 4) | t3;
        default: return (t3 << 8) | (t1 << 4) | t2;
    }
}

// Each thread owns 4 n-values (n0 = q*4). Structured requires A[n]=(n+1)*A0
// and A0 == -1 so exp(dt*A0) == exp(-dt) == (z>=0?E:1)/(1+E).
__device__ __forceinline__ bool load_A4(const float* __restrict__ A_logs,
                                        int k, int d, int n0,
                                        float4& A4, float& A0) {
    A4 = *(const float4*)(A_logs + ((size_t)(k * DD + d) * NN + n0));
    A4.x = -__expf(A4.x); A4.y = -__expf(A4.y);
    A4.z = -__expf(A4.z); A4.w = -__expf(A4.w);
    A0 = -__expf(A_logs[(size_t)(k * DD + d) * NN]);
    float aA0 = fabsf(A0);
    bool s = (fabsf(A0 + 1.0f) <= 1e-5f);
    s = s && (fabsf(A4.x - (float)(n0 + 1) * A0) <= 1e-4f * (float)(n0 + 1) * aA0);
    s = s && (fabsf(A4.y - (float)(n0 + 2) * A0) <= 1e-4f * (float)(n0 + 2) * aA0);
    s = s && (fabsf(A4.z - (float)(n0 + 3) * A0) <= 1e-4f * (float)(n0 + 3) * aA0);
    s = s && (fabsf(A4.w - (float)(n0 + 4) * A0) <= 1e-4f * (float)(n0 + 4) * aA0);
    return s;
}

// 4-lane-group uniform AND of a predicate.
__device__ __forceinline__ bool group_and4(bool v) {
    int si = v ? 1 : 0;
    si &= __shfl_xor(si, 1);
    si &= __shfl_xor(si, 2);
    return si != 0;
}

// ---------------------------------------------------------------------------
// K1 scan body, register-software-pipelined: at each 4-step iteration, copy
// the prefetched batch (delta row, 4xb, 4xc, 4xu) to cur and ISSUE the next
// batch's LDS loads before computing — LDS latency hides under ~100 VALU ops.
// All state in named float4s (R13 lesson: no indexable arrays).
// ---------------------------------------------------------------------------
template<bool S>
__device__ __forceinline__ void scanA_body(
    float* xs, const float* sdbl, int k, int c,
    int d, int q, int n0, float4 A4,
    float4 w0, float4 w1, float bz, float Dval,
    float* __restrict__ S_g, float* __restrict__ dtsum)
{
    float4 h = make_float4(0.f, 0.f, 0.f, 0.f);
    float dsum = 0.0f;

    // ---- prefetch batch 0 (rows 0..3) ----
    float4 r0 = *(const float4*)(sdbl + q * SDST);
    float4 r1 = *(const float4*)(sdbl + q * SDST + 4);
    float4 pb0 = *(const float4*)(&sdbl[0 * SDST + 8 + n0]);
    float4 pb1 = *(const float4*)(&sdbl[1 * SDST + 8 + n0]);
    float4 pb2 = *(const float4*)(&sdbl[2 * SDST + 8 + n0]);
    float4 pb3 = *(const float4*)(&sdbl[3 * SDST + 8 + n0]);
    float4 pc0 = *(const float4*)(&sdbl[0 * SDST + 24 + n0]);
    float4 pc1 = *(const float4*)(&sdbl[1 * SDST + 24 + n0]);
    float4 pc2 = *(const float4*)(&sdbl[2 * SDST + 24 + n0]);
    float4 pc3 = *(const float4*)(&sdbl[3 * SDST + 24 + n0]);
    float pu0 = xs[0 * XST + d], pu1 = xs[1 * XST + d];
    float pu2 = xs[2 * XST + d], pu3 = xs[3 * XST + d];

    #pragma unroll 1
    for (int i4 = 0; i4 < LC; i4 += 4) {
        // cur <- prefetched
        float4 cr0 = r0, cr1 = r1;
        float4 b0 = pb0, b1 = pb1, b2 = pb2, b3 = pb3;
        float4 c0 = pc0, c1 = pc1, c2 = pc2, c3 = pc3;
        float u0 = pu0, u1 = pu1, u2 = pu2, u3 = pu3;

        // issue next batch (last iter: dummy row-0 reloads, results unused;
        // rows i4+4..i4+7 are not yet written by any y-store -> safe)
        int nx = (i4 + 4 < LC) ? (i4 + 4) : 0;
        r0 = *(const float4*)(sdbl + (nx + q) * SDST);
        r1 = *(const float4*)(sdbl + (nx + q) * SDST + 4);
        pb0 = *(const float4*)(&sdbl[(nx + 0) * SDST + 8 + n0]);
        pb1 = *(const float4*)(&sdbl[(nx + 1) * SDST + 8 + n0]);
        pb2 = *(const float4*)(&sdbl[(nx + 2) * SDST + 8 + n0]);
        pb3 = *(const float4*)(&sdbl[(nx + 3) * SDST + 8 + n0]);
        pc0 = *(const float4*)(&sdbl[(nx + 0) * SDST + 24 + n0]);
        pc1 = *(const float4*)(&sdbl[(nx + 1) * SDST + 24 + n0]);
        pc2 = *(const float4*)(&sdbl[(nx + 2) * SDST + 24 + n0]);
        pc3 = *(const float4*)(&sdbl[(nx + 3) * SDST + 24 + n0]);
        pu0 = xs[(nx + 0) * XST + d]; pu1 = xs[(nx + 1) * XST + d];
        pu2 = xs[(nx + 2) * XST + d]; pu3 = xs[(nx + 3) * XST + d];

        // delta for this lane's row (i4+q) from cur regs
        float z = bz + w0.x * cr0.x + w0.y * cr0.y + w0.z * cr0.z + w0.w * cr0.w
                     + w1.x * cr1.x + w1.y * cr1.y + w1.z * cr1.z + w1.w * cr1.w;
        float E = __expf(-fabsf(z));
        float opE = 1.0f + E;
        float dt_me = fmaxf(z, 0.0f) + __logf(opE);
        float qp_me = 0.0f;
        if constexpr (S)
            qp_me = (z >= 0.0f ? E : 1.0f) * __builtin_amdgcn_rcpf(opE);

#define K1_STEP(s, bb, cc, uu)                                               \
        {                                                                    \
            float dt = __shfl(dt_me, s, 4);                                  \
            float4 e;                                                        \
            if constexpr (S) {                                               \
                float qp = __shfl(qp_me, s, 4);                              \
                float qp2 = qp * qp, qp4 = qp2 * qp2, qp8 = qp4 * qp4;       \
                float p = qp * ((q & 1) ? qp4 : 1.0f)                        \
                             * ((q & 2) ? qp8 : 1.0f);                       \
                e.x = p; e.y = p * qp; e.z = e.y * qp; e.w = e.z * qp;       \
            } else {                                                         \
                e.x = __expf(dt * A4.x); e.y = __expf(dt * A4.y);            \
                e.z = __expf(dt * A4.z); e.w = __expf(dt * A4.w);            \
            }                                                                \
            dsum += dt;                                                      \
            float tu = dt * (uu);                                            \
            h.x = e.x * h.x + tu * (bb).x;  h.y = e.y * h.y + tu * (bb).y;   \
            h.z = e.z * h.z + tu * (bb).z;  h.w = e.w * h.w + tu * (bb).w;   \
            float yp = (h.x * (cc).x + h.y * (cc).y)                         \
                     + (h.z * (cc).z + h.w * (cc).w);                        \
            float s1 = yp + __shfl_xor(yp, 1);                               \
            float s2 = s1 + __shfl_xor(s1, 2);                               \
            if (q == 0) xs[(i4 + s) * XST + d] = s2 + Dval * (uu);           \
        }
        K1_STEP(0, b0, c0, u0)
        K1_STEP(1, b1, c1, u1)
        K1_STEP(2, b2, c2, u2)
        K1_STEP(3, b3, c3, u3)
#undef K1_STEP
    }

    *(float4*)(S_g + (((size_t)(k * NC + c) * DD + d) * NN + n0)) = h;
    if (q == 0) dtsum[(k * NC + c) * DD + d] = dsum;
}

// ---------------------------------------------------------------------------
// K1: proj GEMM + phase A local scan. Block = (k, 32-l chunk), 512 threads,
// thread = (d, q) 4-way n-split. (512,4): VGPR cap 128 for the pipeline regs.
// ---------------------------------------------------------------------------
__global__ __launch_bounds__(512, 4) void k1_proj_scanA(
    const float* __restrict__ x, const float* __restrict__ Wp,
    const float* __restrict__ Wdt, const float* __restrict__ bias,
    const float* __restrict__ A_logs, const float* __restrict__ Ds,
    float* __restrict__ S_g, float* __restrict__ dtsum,
    float* __restrict__ oy, float* __restrict__ xdbl)
{
    const int blk = blockIdx.x;
    const int k = blk >> 7;
    const int c = blk & 127;
    const int l0 = c * LC;
    const int t = threadIdx.x;

    __shared__ __align__(16) float xs[LC * XST];    // x-tile [l][d]; y overwrites
    __shared__ __align__(16) float sdbl[LC * SDST]; // x_dbl [l][ch]
    __shared__ int pos_s[LC];

    if (t < LC) pos_s[t] = pos_of(k, l0 + t);
    __syncthreads();

    // ---- stage x tile: 2 passes x 16 rows x 32 lanes b128 (coalesced) ----
    {
        int lane32 = t & 31, rowi = t >> 5;   // rowi 0..15
        #pragma unroll
        for (int p = 0; p < 2; p++) {
            int l = p * 16 + rowi;
            float4 v = *(const float4*)(x + (size_t)pos_s[l] * DD + lane32 * 4);
            *(float4*)(&xs[l * XST + lane32 * 4]) = v;
        }
    }
    __syncthreads();

    // ---- projection GEMM (R8-exact, first 256 threads) ----
    if (t < 256) {
        int l = t & 31, cg = t >> 5;          // cg 0..7, 5 channels each
        float acc[5];
        #pragma unroll
        for (int j = 0; j < 5; j++) acc[j] = 0.0f;
        const float* wk = Wp + (size_t)(k * 40 + cg * 5) * DD;
        for (int d4 = 0; d4 < DD; d4 += 4) {
            float4 xv = *(const float4*)(&xs[l * XST + d4]);
            #pragma unroll
            for (int j = 0; j < 5; j++) {
                const float* w = wk + j * DD + d4;
                acc[j] += xv.x * w[0] + xv.y * w[1] + xv.z * w[2] + xv.w * w[3];
            }
        }
        #pragma unroll
        for (int j = 0; j < 5; j++) sdbl[l * SDST + cg * 5 + j] = acc[j];
    }
    __syncthreads();

    // ---- spill x_dbl tile for K3 (352 float4s, single shot) ----
    if (t < XDBL_TILE / 4) {
        ((float4*)(xdbl + (size_t)blk * XDBL_TILE))[t] = ((const float4*)sdbl)[t];
    }

    // ---- phase A scan: thread = (d, quarter) ----
    const int d = t >> 2, q = t & 3, n0 = q * 4;
    float4 A4; float A0;
    bool structured = group_and4(load_A4(A_logs, k, d, n0, A4, A0));
    const float4* wp4 = (const float4*)(Wdt + (size_t)(k * DD + d) * RR);
    const float4 w0 = wp4[0], w1 = wp4[1];
    const float bz = bias[k * DD + d];
    const float Dval = Ds[k * DD + d];

    if (structured)
        scanA_body<true>(xs, sdbl, k, c, d, q, n0, A4, w0, w1, bz,
                         Dval, S_g, dtsum);
    else
        scanA_body<false>(xs, sdbl, k, c, d, q, n0, A4, w0, w1, bz,
                          Dval, S_g, dtsum);

    // ---- transposed y store: lane q covers rows q*8..q*8+7 of column d ----
    {
        float* base = oy + ((size_t)(k * DD + d)) * LL + l0 + q * 8;
        #pragma unroll
        for (int p = 0; p < 2; p++) {
            int j = p * 4;
            float4 v = make_float4(xs[(q * 8 + j + 0) * XST + d],
                                   xs[(q * 8 + j + 1) * XST + d],
                                   xs[(q * 8 + j + 2) * XST + d],
                                   xs[(q * 8 + j + 3) * XST + d]);
            *(float4*)(base + j) = v;
        }
    }
}

// ---------------------------------------------------------------------------
// K2: sequential combine across 128 chunks; S <- true h0, in place.
// ---------------------------------------------------------------------------
__global__ __launch_bounds__(256) void k2_combine(
    float* __restrict__ S_g, const float* __restrict__ dtsum,
    const float* __restrict__ A_logs)
{
    int tid = blockIdx.x * 256 + threadIdx.x;   // k*2048 + d*16 + n
    int kk = tid >> 11, rem = tid & 2047, dd2 = rem >> 4;
    float Ac = -__expf(A_logs[tid]);
    float hh = 0.0f;
    #pragma unroll 8
    for (int c2 = 0; c2 < NC; c2++) {
        size_t base = ((size_t)(kk * NC + c2)) * 2048 + rem;
        float s = S_g[base];
        float dsv = dtsum[(kk * NC + c2) * DD + dd2];
        S_g[base] = hh;
        hh = s + __expf(dsv * Ac) * hh;
    }
}

// ---------------------------------------------------------------------------
// K3 body, register-software-pipelined like K1 (delta row + 4xc per batch).
// ---------------------------------------------------------------------------
template<bool S>
__device__ __forceinline__ void corr_body(
    float* ybuf, const float* sdbl, int d, int q, int n0,
    float4 A4, float4 h0, float4 w0, float4 w1, float bz)
{
    float Q = 1.0f;      // structured running product
    float Dsum = 0.0f;   // generic running sum

    float4 r0 = *(const float4*)(sdbl + q * SDST);
    float4 r1 = *(const float4*)(sdbl + q * SDST + 4);
    float4 pc0 = *(const float4*)(&sdbl[0 * SDST + 24 + n0]);
    float4 pc1 = *(const float4*)(&sdbl[1 * SDST + 24 + n0]);
    float4 pc2 = *(const float4*)(&sdbl[2 * SDST + 24 + n0]);
    float4 pc3 = *(const float4*)(&sdbl[3 * SDST + 24 + n0]);

    #pragma unroll 1
    for (int i4 = 0; i4 < LC; i4 += 4) {
        float4 cr0 = r0, cr1 = r1;
        float4 c0 = pc0, c1 = pc1, c2 = pc2, c3 = pc3;

        int nx = (i4 + 4 < LC) ? (i4 + 4) : 0;
        r0 = *(const float4*)(sdbl + (nx + q) * SDST);
        r1 = *(const float4*)(sdbl + (nx + q) * SDST + 4);
        pc0 = *(const float4*)(&sdbl[(nx + 0) * SDST + 24 + n0]);
        pc1 = *(const float4*)(&sdbl[(nx + 1) * SDST + 24 + n0]);
        pc2 = *(const float4*)(&sdbl[(nx + 2) * SDST + 24 + n0]);
        pc3 = *(const float4*)(&sdbl[(nx + 3) * SDST + 24 + n0]);

        float z = bz + w0.x * cr0.x + w0.y * cr0.y + w0.z * cr0.z + w0.w * cr0.w
                     + w1.x * cr1.x + w1.y * cr1.y + w1.z * cr1.z + w1.w * cr1.w;
        float E = __expf(-fabsf(z));
        float opE = 1.0f + E;
        float dt_me = fmaxf(z, 0.0f) + __logf(opE);
        float qp_me = 0.0f;
        if constexpr (S)
            qp_me = (z >= 0.0f ? E : 1.0f) * __builtin_amdgcn_rcpf(opE);

#define K3_STEP(s, cc)                                                       \
        {                                                                    \
            float yp;                                                        \
            if constexpr (S) {                                               \
                Q *= __shfl(qp_me, s, 4);                                    \
                float sH =         h0.w * (cc).w;                            \
                sH = sH * Q + h0.z * (cc).z;                                 \
                sH = sH * Q + h0.y * (cc).y;                                 \
                sH = sH * Q + h0.x * (cc).x;                                 \
                float Q2 = Q * Q, Q4 = Q2 * Q2, Q8 = Q4 * Q4;                \
                float Qp = Q * ((q & 1) ? Q4 : 1.0f)                         \
                             * ((q & 2) ? Q8 : 1.0f);                        \
                yp = sH * Qp;                                                \
            } else {                                                         \
                Dsum += __shfl(dt_me, s, 4);                                 \
                yp = __expf(Dsum * A4.x) * h0.x * (cc).x                     \
                   + __expf(Dsum * A4.y) * h0.y * (cc).y                     \
                   + __expf(Dsum * A4.z) * h0.z * (cc).z                     \
                   + __expf(Dsum * A4.w) * h0.w * (cc).w;                    \
            }                                                                \
            float s1 = yp + __shfl_xor(yp, 1);                               \
            float s2 = s1 + __shfl_xor(s1, 2);                               \
            if (q == 0) ybuf[(i4 + s) * XST + d] = s2;                       \
        }
        K3_STEP(0, c0)
        K3_STEP(1, c1)
        K3_STEP(2, c2)
        K3_STEP(3, c3)
#undef K3_STEP
    }
}

__global__ __launch_bounds__(512, 4) void k3_corr(
    const float* __restrict__ Wdt, const float* __restrict__ bias,
    const float* __restrict__ A_logs, const float* __restrict__ S_g,
    const float* __restrict__ xdbl, float* __restrict__ oy)
{
    const int blk = blockIdx.x;
    const int k = blk >> 7;
    const int c = blk & 127;
    if (c == 0) return;                 // chunk 0 has h0 = 0
    const int l0 = c * LC;
    const int t = threadIdx.x;

    __shared__ __align__(16) float sdbl[LC * SDST];
    __shared__ __align__(16) float ybuf[LC * XST];
    if (t < XDBL_TILE / 4) {
        ((float4*)sdbl)[t] = ((const float4*)(xdbl + (size_t)blk * XDBL_TILE))[t];
    }
    __syncthreads();

    const int d = t >> 2, q = t & 3, n0 = q * 4;
    float4 A4; float A0;
    bool structured = group_and4(load_A4(A_logs, k, d, n0, A4, A0));
    const float4* wp4 = (const float4*)(Wdt + (size_t)(k * DD + d) * RR);
    const float4 w0 = wp4[0], w1 = wp4[1];
    const float bz = bias[k * DD + d];

    float4 h0 = *(const float4*)(S_g + (((size_t)(k * NC + c) * DD + d) * NN + n0));

    if (structured)
        corr_body<true>(ybuf, sdbl, d, q, n0, A4, h0, w0, w1, bz);
    else
        corr_body<false>(ybuf, sdbl, d, q, n0, A4, h0, w0, w1, bz);

    // ---- transposed RMW of oy tile: lane q covers rows q*8..q*8+7 ----
    {
        float* base = oy + ((size_t)(k * DD + d)) * LL + l0 + q * 8;
        #pragma unroll
        for (int p = 0; p < 2; p++) {
            int j = p * 4;
            float4 v = *(float4*)(base + j);
            v.x += ybuf[(q * 8 + j + 0) * XST + d];
            v.y += ybuf[(q * 8 + j + 1) * XST + d];
            v.z += ybuf[(q * 8 + j + 2) * XST + d];
            v.w += ybuf[(q * 8 + j + 3) * XST + d];
            *(float4*)(base + j) = v;
        }
    }
}

// ---------------------------------------------------------------------------
// K4: restore + merge (reference's (D,L)-flat reshape semantics), float4.
// ---------------------------------------------------------------------------
__global__ __launch_bounds__(256) void k4_merge(
    const float* __restrict__ out_y, const float* __restrict__ mw,
    const float* __restrict__ mb, float* __restrict__ out)
{
    int idx4 = blockIdx.x * 256 + threadIdx.x;   // float4 index
    int dd4 = (idx4 & 31) * 4;
    int p = idx4 >> 5;
    int i3 = p & 15, i2 = (p >> 4) & 15, i1 = (p >> 8) & 15;

    float b = mb[0];
    float4 accv = make_float4(b, b, b, b);
    #pragma unroll
    for (int k = 0; k < 12; k++) {
        int a1 = i1, a2 = i2, a3 = i3;
        if (k & 1) { a1 = 15 - i1; a2 = 15 - i2; a3 = 15 - i3; }
        int j1, j2, j3;
        switch (k >> 1) {
            case 0:  j1 = a1; j2 = a2; j3 = a3; break;
            case 1:  j1 = a1; j2 = a3; j3 = a2; break;
            case 2:  j1 = a3; j2 = a2; j3 = a1; break;
            case 3:  j1 = a3; j2 = a1; j3 = a2; break;
            case 4:  j1 = a2; j2 = a1; j3 = a3; break;
            default: j1 = a2; j2 = a3; j3 = a1; break;
        }
        int jb = (j1 << 8) | (j2 << 4) | j3;
        float4 v = *(const float4*)(out_y + (size_t)k * (DD * LL) + (jb >> 5) * LL
                                    + ((jb & 31) << 7) + dd4);
        float w = mw[k];
        accv.x += w * v.x; accv.y += w * v.y;
        accv.z += w * v.z; accv.w += w * v.w;
    }
    *(float4*)(out + (size_t)p * DD + dd4) = accv;
}

extern "C" void kernel_launch(void* const* d_in, const int* in_sizes, int n_in,
                              void* d_out, int out_size, void* d_ws, size_t ws_size,
                              hipStream_t stream) {
    const float* x      = (const float*)d_in[0];
    const float* Wp     = (const float*)d_in[1];
    const float* Wdt    = (const float*)d_in[2];
    const float* bias   = (const float*)d_in[3];
    const float* A_logs = (const float*)d_in[4];
    const float* Ds     = (const float*)d_in[5];
    const float* mw     = (const float*)d_in[6];
    const float* mb     = (const float*)d_in[7];
    float* out = (float*)d_out;

    float* ws   = (float*)d_ws;
    float* S_g  = ws;                                 // K*NC*D*N = 1572864
    float* dts  = S_g + (size_t)KK * NC * DD * NN;    // K*NC*D   =   98304
    float* oy   = dts + (size_t)KK * NC * DD;         // K*D*L    = 6291456
    float* xdbl = oy + (size_t)KK * DD * LL;          // 1536*1408 = 2162688

    k1_proj_scanA<<<dim3(KK * NC), dim3(512), 0, stream>>>(
        x, Wp, Wdt, bias, A_logs, Ds, S_g, dts, oy, xdbl);
    k2_combine<<<dim3(KK * DD * NN / 256), dim3(256), 0, stream>>>(S_g, dts, A_logs);
    k3_corr<<<dim3(KK * NC), dim3(512), 0, stream>>>(Wdt, bias, A_logs, S_g, xdbl, oy);
    k4_merge<<<dim3(LL * DD / 1024), dim3(256), 0, stream>>>(oy, mw, mb, out);
}

// Round 18
// 154.793 us; speedup vs baseline: 1.1244x; 1.1244x over previous
//
#include <hip/hip_runtime.h>

#define KK 12
#define LL 4096
#define DD 128
#define NN 16
#define RR 8
#define NC 128             // chunks (one per block)
#define LC 32              // chunk length = l-tile per block
#define XST 132            // x-tile / ybuf LDS stride (floats)
#define SDST 44            // x_dbl LDS row stride (floats)
#define XDBL_TILE (LC * SDST)   // 1408 floats per (k,chunk) tile

__device__ __forceinline__ int pos_of(int k, int l) {
    int o = k >> 1;
    int le = (k & 1) ? (4095 - l) : l;
    int t1 = le >> 8, t2 = (le >> 4) & 15, t3 = le & 15;
    switch (o) {
        case 0:  return (t1 << 8) | (t2 << 4) | t3;
        case 1:  return (t1 << 8) | (t3 << 4) | t2;
        case 2:  return (t3 << 8) | (t2 << 4) | t1;
        case 3:  return (t2 << 8) | (t3 << 4) | t1;
        case 4:  return (t2 << 8) | (t1 << 4) | t3;
        default: return (t3 << 8) | (t1 << 4) | t2;
    }
}

__device__ __forceinline__ float delta_row_z(const float* sdbl, int l,
                                             float4 w0, float4 w1, float bz) {
    const float4* dr = (const float4*)(sdbl + l * SDST);
    float4 r0 = dr[0], r1 = dr[1];
    return bz + w0.x * r0.x + w0.y * r0.y + w0.z * r0.z + w0.w * r0.w
              + w1.x * r1.x + w1.y * r1.y + w1.z * r1.z + w1.w * r1.w;
}

// Structured requires A[n] = (n+1)*A0 AND A0 == -1 (true for this problem:
// A_logs = log(1..16)), so that exp(dt*A0) == exp(-dt) == (z>=0?E:1)/(1+E).
__device__ __forceinline__ bool load_A8(const float* __restrict__ A_logs,
                                        int k, int d, int n0, float* A8, float& A0) {
    const float4* ap = (const float4*)(A_logs + ((size_t)(k * DD + d) * NN + n0));
    float4 a0 = ap[0], a1 = ap[1];
    A8[0] = -__expf(a0.x); A8[1] = -__expf(a0.y);
    A8[2] = -__expf(a0.z); A8[3] = -__expf(a0.w);
    A8[4] = -__expf(a1.x); A8[5] = -__expf(a1.y);
    A8[6] = -__expf(a1.z); A8[7] = -__expf(a1.w);
    A0 = -__expf(A_logs[(size_t)(k * DD + d) * NN]);
    bool s = (fabsf(A0 + 1.0f) <= 1e-5f);
    #pragma unroll
    for (int j = 0; j < 8; j++) {
        float m = (float)(n0 + j + 1);
        s = s && (fabsf(A8[j] - m * A0) <= 1e-4f * m * fabsf(A0));
    }
    return s;
}

// ---------------------------------------------------------------------------
// One scan step. Structured path takes q = exp(-dt) directly (no exp here).
// ---------------------------------------------------------------------------
template<bool S>
__device__ __forceinline__ void scan_step(
    float* xs, const float* sdbl, int i, int d, int half, int n0,
    const float* A8, float dt, float q, float Dval, float* h, float& dsum)
{
    float u = xs[i * XST + d];
    dsum += dt;
    float tu = dt * u;
    float e[8];
    if constexpr (S) {
        float q2 = q * q, q4 = q2 * q2, q8 = q4 * q4;
        e[0] = half ? q8 * q : q;
        #pragma unroll
        for (int j = 1; j < 8; j++) e[j] = e[j - 1] * q;
    } else {
        #pragma unroll
        for (int j = 0; j < 8; j++) e[j] = __expf(dt * A8[j]);
    }
    const float4* bp = (const float4*)(&sdbl[i * SDST + 8 + n0]);
    float4 b0 = bp[0], b1 = bp[1];
    const float4* cp = (const float4*)(&sdbl[i * SDST + 24 + n0]);
    float4 c0 = cp[0], c1 = cp[1];
    h[0] = e[0] * h[0] + tu * b0.x;  h[1] = e[1] * h[1] + tu * b0.y;
    h[2] = e[2] * h[2] + tu * b0.z;  h[3] = e[3] * h[3] + tu * b0.w;
    h[4] = e[4] * h[4] + tu * b1.x;  h[5] = e[5] * h[5] + tu * b1.y;
    h[6] = e[6] * h[6] + tu * b1.z;  h[7] = e[7] * h[7] + tu * b1.w;
    float yp = h[0] * c0.x + h[1] * c0.y + h[2] * c0.z + h[3] * c0.w
             + h[4] * c1.x + h[5] * c1.y + h[6] * c1.z + h[7] * c1.w;
    float yv = yp + __shfl_xor(yp, 1) + Dval * u;
    if (!half) xs[i * XST + d] = yv;
}

// ---------------------------------------------------------------------------
// K1 scan body. Pairwise delta: lane `half` computes Delta for row i+half,
// partner's value arrives via quad-perm shfl_xor — halves z/softplus cost.
// ---------------------------------------------------------------------------
template<bool S>
__device__ __forceinline__ void scanA_body(
    float* xs, const float* sdbl, int k, int c,
    int d, int half, int n0, const float* A8,
    float4 w0, float4 w1, float bz, float Dval,
    float* __restrict__ S_g, float* __restrict__ dtsum)
{
    float h[8] = {0, 0, 0, 0, 0, 0, 0, 0};
    float dsum = 0.0f;

    #pragma unroll 2
    for (int i2 = 0; i2 < LC; i2 += 2) {
        float z = delta_row_z(sdbl, i2 + half, w0, w1, bz);
        float E = __expf(-fabsf(z));
        float opE = 1.0f + E;
        float dt = fmaxf(z, 0.0f) + __logf(opE);
        float q = 0.0f;
        if constexpr (S)
            q = (z >= 0.0f ? E : 1.0f) * __builtin_amdgcn_rcpf(opE);
        float dto = __shfl_xor(dt, 1);
        float qo  = S ? __shfl_xor(q, 1) : 0.0f;
        float dt0 = half ? dto : dt,  dt1 = half ? dt : dto;
        float q0  = half ? qo  : q,   q1  = half ? q  : qo;
        scan_step<S>(xs, sdbl, i2,     d, half, n0, A8, dt0, q0, Dval, h, dsum);
        scan_step<S>(xs, sdbl, i2 + 1, d, half, n0, A8, dt1, q1, Dval, h, dsum);
    }

    float4* sp = (float4*)(S_g + (((size_t)(k * NC + c) * DD + d) * NN + n0));
    sp[0] = make_float4(h[0], h[1], h[2], h[3]);
    sp[1] = make_float4(h[4], h[5], h[6], h[7]);
    if (!half) dtsum[(k * NC + c) * DD + d] = dsum;
}

// ---------------------------------------------------------------------------
// K1: proj GEMM + phase A local scan. Block = (k, 32-l chunk), 256 threads.
// LDS 22.7 KB; (256,4) -> 44 VGPR, no scratch (verified R2/R8 counters).
// ---------------------------------------------------------------------------
__global__ __launch_bounds__(256, 4) void k1_proj_scanA(
    const float* __restrict__ x, const float* __restrict__ Wp,
    const float* __restrict__ Wdt, const float* __restrict__ bias,
    const float* __restrict__ A_logs, const float* __restrict__ Ds,
    float* __restrict__ S_g, float* __restrict__ dtsum,
    float* __restrict__ oy, float* __restrict__ xdbl)
{
    const int blk = blockIdx.x;
    const int k = blk >> 7;
    const int c = blk & 127;
    const int l0 = c * LC;
    const int t = threadIdx.x;

    __shared__ __align__(16) float xs[LC * XST];    // x-tile [l][d]; y overwrites
    __shared__ __align__(16) float sdbl[LC * SDST]; // x_dbl [l][c]
    __shared__ int pos_s[LC];

    if (t < LC) pos_s[t] = pos_of(k, l0 + t);
    __syncthreads();

    // ---- stage x tile: 4 passes x 8 rows x 32 lanes b128 (coalesced) ----
    {
        int lane32 = t & 31, rowi = t >> 5;
        #pragma unroll
        for (int p = 0; p < 4; p++) {
            int l = p * 8 + rowi;
            float4 v = *(const float4*)(x + (size_t)pos_s[l] * DD + lane32 * 4);
            *(float4*)(&xs[l * XST + lane32 * 4]) = v;
        }
    }
    __syncthreads();

    // ---- projection GEMM: group cg (of 8) computes 5 of 40 channels ----
    {
        int l = t & 31, cg = t >> 5;
        float acc[5];
        #pragma unroll
        for (int j = 0; j < 5; j++) acc[j] = 0.0f;
        const float* wk = Wp + (size_t)(k * 40 + cg * 5) * DD;
        for (int d4 = 0; d4 < DD; d4 += 4) {
            float4 xv = *(const float4*)(&xs[l * XST + d4]);
            #pragma unroll
            for (int j = 0; j < 5; j++) {
                const float* w = wk + j * DD + d4;   // wave-uniform -> s_load
                acc[j] += xv.x * w[0] + xv.y * w[1] + xv.z * w[2] + xv.w * w[3];
            }
        }
        #pragma unroll
        for (int j = 0; j < 5; j++) sdbl[l * SDST + cg * 5 + j] = acc[j];
    }
    __syncthreads();

    // ---- spill x_dbl tile for K3 ----
    {
        const float4* s4 = (const float4*)sdbl;
        float4* g4 = (float4*)(xdbl + (size_t)blk * XDBL_TILE);
        for (int idx = t; idx < XDBL_TILE / 4; idx += 256) g4[idx] = s4[idx];
    }

    // ---- phase A scan: thread = (d, n-half) ----
    const int d = t >> 1, half = t & 1, n0 = half * 8;
    float A8[8], A0;
    bool structured = load_A8(A_logs, k, d, n0, A8, A0);
    const float4* wp4 = (const float4*)(Wdt + (size_t)(k * DD + d) * RR);
    const float4 w0 = wp4[0], w1 = wp4[1];
    const float bz = bias[k * DD + d];
    const float Dval = Ds[k * DD + d];

    if (structured)
        scanA_body<true>(xs, sdbl, k, c, d, half, n0, A8, w0, w1, bz,
                         Dval, S_g, dtsum);
    else
        scanA_body<false>(xs, sdbl, k, c, d, half, n0, A8, w0, w1, bz,
                          Dval, S_g, dtsum);

    // ---- transposed y store (intra-wave pair data; no barrier needed) ----
    {
        float* base = oy + ((size_t)(k * DD + d)) * LL + l0 + half * 16;
        #pragma unroll
        for (int p = 0; p < 4; p++) {
            int j = p * 4;
            float4 v = make_float4(xs[(half * 16 + j + 0) * XST + d],
                                   xs[(half * 16 + j + 1) * XST + d],
                                   xs[(half * 16 + j + 2) * XST + d],
                                   xs[(half * 16 + j + 3) * XST + d]);
            *(float4*)(base + j) = v;
        }
    }
}

// ---------------------------------------------------------------------------
// K2: PARALLEL segmented scan over 128 chunks. 8 segment-threads per scan
// (16 chunks each): phase 1 composes each segment's affine map (S,W) for
// h -> s + w*h; phase 2 LDS-exchanges and computes segment-start h (<=7
// affine applies); phase 3 re-walks writing exclusive prefixes into S_g.
// 768 blocks x 256 threads = 3072 waves (vs serial version's 384).
// ---------------------------------------------------------------------------
__global__ __launch_bounds__(256) void k2_combine(
    float* __restrict__ S_g, const float* __restrict__ dtsum,
    const float* __restrict__ A_logs)
{
    const int t = threadIdx.x;
    const int s_l = t & 31;                  // scan-in-block 0..31
    const int g   = t >> 5;                  // segment 0..7
    const int sid = blockIdx.x * 32 + s_l;   // = kk*2048 + rem
    const int kk  = sid >> 11, rem = sid & 2047, dd2 = rem >> 4;
    const float Ac = -__expf(A_logs[sid]);

    __shared__ float lsS[8][32];
    __shared__ float lsW[8][32];

    const int c0 = g * 16;

    // ---- phase 1: segment composition (S,W); loads independent -> batched
    float S = 0.0f, W = 1.0f;
    #pragma unroll 4
    for (int i = 0; i < 16; i++) {
        int c = c0 + i;
        size_t base = ((size_t)(kk * NC + c)) * 2048 + rem;
        float s = S_g[base];
        float w = __expf(dtsum[(kk * NC + c) * DD + dd2] * Ac);
        S = s + w * S;
        W = w * W;
    }
    lsS[g][s_l] = S;
    lsW[g][s_l] = W;
    __syncthreads();

    // ---- phase 2: segment-start h = (seg 0..g-1 composed) applied to 0
    float h = 0.0f;
    for (int j = 0; j < g; j++)
        h = lsS[j][s_l] + lsW[j][s_l] * h;

    // ---- phase 3: write exclusive prefixes (same-thread chunks only; the
    // only cross-thread exchange was via LDS above -> no global hazard)
    #pragma unroll 4
    for (int i = 0; i < 16; i++) {
        int c = c0 + i;
        size_t base = ((size_t)(kk * NC + c)) * 2048 + rem;
        float s = S_g[base];
        float w = __expf(dtsum[(kk * NC + c) * DD + dd2] * Ac);
        S_g[base] = h;
        h = s + w * h;
    }
}

// ---------------------------------------------------------------------------
// K3 body: y(l) += C(l) . (exp(Dsum_l * A) (.) h0).
// Structured: running product Q = exp(-Dsum) (one mul per step, no exp/log),
// per-n powers folded into a 7-FMA Horner:  yp = Q^{n0+1} * sum_j g_j Q^j.
// ---------------------------------------------------------------------------
template<bool S>
__device__ __forceinline__ void corr_body(
    float* ybuf, const float* sdbl, int d, int half, int n0,
    const float* A8, const float* h0, float4 w0, float4 w1, float bz)
{
    if constexpr (S) {
        float Q = 1.0f;
        #pragma unroll 2
        for (int i2 = 0; i2 < LC; i2 += 2) {
            float z = delta_row_z(sdbl, i2 + half, w0, w1, bz);
            float E = __expf(-fabsf(z));
            float q = (z >= 0.0f ? E : 1.0f) * __builtin_amdgcn_rcpf(1.0f + E);
            float qo = __shfl_xor(q, 1);
            float q0 = half ? qo : q, q1 = half ? q : qo;
            #pragma unroll
            for (int s = 0; s < 2; s++) {
                int i = i2 + s;
                Q *= (s ? q1 : q0);
                const float4* cp = (const float4*)(&sdbl[i * SDST + 24 + n0]);
                float4 c0 = cp[0], c1 = cp[1];
                float sH =           h0[7] * c1.w;
                sH = sH * Q + h0[6] * c1.z;
                sH = sH * Q + h0[5] * c1.y;
                sH = sH * Q + h0[4] * c1.x;
                sH = sH * Q + h0[3] * c0.w;
                sH = sH * Q + h0[2] * c0.z;
                sH = sH * Q + h0[1] * c0.y;
                sH = sH * Q + h0[0] * c0.x;
                float Q2 = Q * Q, Q4 = Q2 * Q2, Q8 = Q4 * Q4;
                float Qp = half ? Q8 * Q : Q;
                float yp = sH * Qp;
                float yv = yp + __shfl_xor(yp, 1);
                if (!half) ybuf[i * XST + d] = yv;
            }
        }
    } else {
        float Dsum = 0.0f;
        #pragma unroll 2
        for (int i2 = 0; i2 < LC; i2 += 2) {
            float z = delta_row_z(sdbl, i2 + half, w0, w1, bz);
            float E = __expf(-fabsf(z));
            float dt = fmaxf(z, 0.0f) + __logf(1.0f + E);
            float dto = __shfl_xor(dt, 1);
            float dt0 = half ? dto : dt, dt1 = half ? dt : dto;
            #pragma unroll
            for (int s = 0; s < 2; s++) {
                int i = i2 + s;
                Dsum += (s ? dt1 : dt0);
                float e[8];
                #pragma unroll
                for (int j = 0; j < 8; j++) e[j] = __expf(Dsum * A8[j]);
                const float4* cp = (const float4*)(&sdbl[i * SDST + 24 + n0]);
                float4 c0 = cp[0], c1 = cp[1];
                float yp = e[0]*h0[0]*c0.x + e[1]*h0[1]*c0.y + e[2]*h0[2]*c0.z + e[3]*h0[3]*c0.w
                         + e[4]*h0[4]*c1.x + e[5]*h0[5]*c1.y + e[6]*h0[6]*c1.z + e[7]*h0[7]*c1.w;
                float yv = yp + __shfl_xor(yp, 1);
                if (!half) ybuf[i * XST + d] = yv;
            }
        }
    }
}

__global__ __launch_bounds__(256, 4) void k3_corr(
    const float* __restrict__ Wdt, const float* __restrict__ bias,
    const float* __restrict__ A_logs, const float* __restrict__ S_g,
    const float* __restrict__ xdbl, float* __restrict__ oy)
{
    const int blk = blockIdx.x;
    const int k = blk >> 7;
    const int c = blk & 127;
    if (c == 0) return;                 // chunk 0 has h0 = 0
    const int l0 = c * LC;
    const int t = threadIdx.x;

    __shared__ __align__(16) float sdbl[LC * SDST];
    __shared__ __align__(16) float ybuf[LC * XST];
    {
        const float4* g4 = (const float4*)(xdbl + (size_t)blk * XDBL_TILE);
        float4* s4 = (float4*)sdbl;
        for (int idx = t; idx < XDBL_TILE / 4; idx += 256) s4[idx] = g4[idx];
    }
    __syncthreads();

    const int d = t >> 1, half = t & 1, n0 = half * 8;
    float A8[8], A0;
    bool structured = load_A8(A_logs, k, d, n0, A8, A0);
    const float4* wp4 = (const float4*)(Wdt + (size_t)(k * DD + d) * RR);
    const float4 w0 = wp4[0], w1 = wp4[1];
    const float bz = bias[k * DD + d];

    float h0[8];
    {
        const float4* hp = (const float4*)(S_g + (((size_t)(k * NC + c) * DD + d) * NN + n0));
        float4 h40 = hp[0], h41 = hp[1];
        h0[0] = h40.x; h0[1] = h40.y; h0[2] = h40.z; h0[3] = h40.w;
        h0[4] = h41.x; h0[5] = h41.y; h0[6] = h41.z; h0[7] = h41.w;
    }

    if (structured)
        corr_body<true>(ybuf, sdbl, d, half, n0, A8, h0, w0, w1, bz);
    else
        corr_body<false>(ybuf, sdbl, d, half, n0, A8, h0, w0, w1, bz);

    // ---- transposed RMW of oy tile (intra-wave pair data) ----
    {
        float* base = oy + ((size_t)(k * DD + d)) * LL + l0 + half * 16;
        #pragma unroll
        for (int p = 0; p < 4; p++) {
            int j = p * 4;
            float4 v = *(float4*)(base + j);
            v.x += ybuf[(half * 16 + j + 0) * XST + d];
            v.y += ybuf[(half * 16 + j + 1) * XST + d];
            v.z += ybuf[(half * 16 + j + 2) * XST + d];
            v.w += ybuf[(half * 16 + j + 3) * XST + d];
            *(float4*)(base + j) = v;
        }
    }
}

// ---------------------------------------------------------------------------
// K4: restore + merge (reference's (D,L)-flat reshape semantics), float4.
// ---------------------------------------------------------------------------
__global__ __launch_bounds__(256) void k4_merge(
    const float* __restrict__ out_y, const float* __restrict__ mw,
    const float* __restrict__ mb, float* __restrict__ out)
{
    int idx4 = blockIdx.x * 256 + threadIdx.x;   // float4 index
    int dd4 = (idx4 & 31) * 4;
    int p = idx4 >> 5;
    int i3 = p & 15, i2 = (p >> 4) & 15, i1 = (p >> 8) & 15;

    float b = mb[0];
    float4 accv = make_float4(b, b, b, b);
    #pragma unroll
    for (int k = 0; k < 12; k++) {
        int a1 = i1, a2 = i2, a3 = i3;
        if (k & 1) { a1 = 15 - i1; a2 = 15 - i2; a3 = 15 - i3; }
        int j1, j2, j3;
        switch (k >> 1) {
            case 0:  j1 = a1; j2 = a2; j3 = a3; break;
            case 1:  j1 = a1; j2 = a3; j3 = a2; break;
            case 2:  j1 = a3; j2 = a2; j3 = a1; break;
            case 3:  j1 = a3; j2 = a1; j3 = a2; break;
            case 4:  j1 = a2; j2 = a1; j3 = a3; break;
            default: j1 = a2; j2 = a3; j3 = a1; break;
        }
        int jb = (j1 << 8) | (j2 << 4) | j3;
        float4 v = *(const float4*)(out_y + (size_t)k * (DD * LL) + (jb >> 5) * LL
                                    + ((jb & 31) << 7) + dd4);
        float w = mw[k];
        accv.x += w * v.x; accv.y += w * v.y;
        accv.z += w * v.z; accv.w += w * v.w;
    }
    *(float4*)(out + (size_t)p * DD + dd4) = accv;
}

extern "C" void kernel_launch(void* const* d_in, const int* in_sizes, int n_in,
                              void* d_out, int out_size, void* d_ws, size_t ws_size,
                              hipStream_t stream) {
    const float* x      = (const float*)d_in[0];
    const float* Wp     = (const float*)d_in[1];
    const float* Wdt    = (const float*)d_in[2];
    const float* bias   = (const float*)d_in[3];
    const float* A_logs = (const float*)d_in[4];
    const float* Ds     = (const float*)d_in[5];
    const float* mw     = (const float*)d_in[6];
    const float* mb     = (const float*)d_in[7];
    float* out = (float*)d_out;

    float* ws   = (float*)d_ws;
    float* S_g  = ws;                                 // K*NC*D*N = 1572864
    float* dts  = S_g + (size_t)KK * NC * DD * NN;    // K*NC*D   =   98304
    float* oy   = dts + (size_t)KK * NC * DD;         // K*D*L    = 6291456
    float* xdbl = oy + (size_t)KK * DD * LL;          // 1536*1408 = 2162688

    k1_proj_scanA<<<dim3(KK * NC), dim3(256), 0, stream>>>(
        x, Wp, Wdt, bias, A_logs, Ds, S_g, dts, oy, xdbl);
    k2_combine<<<dim3(KK * DD * NN / 32), dim3(256), 0, stream>>>(S_g, dts, A_logs);
    k3_corr<<<dim3(KK * NC), dim3(256), 0, stream>>>(Wdt, bias, A_logs, S_g, xdbl, oy);
    k4_merge<<<dim3(LL * DD / 1024), dim3(256), 0, stream>>>(oy, mw, mb, out);
}